// Round 24
// baseline (52.307 us; speedup 1.0000x reference)
//
#include <hip/hip_runtime.h>
#include <math.h>

// ---------------------------------------------------------------------------
// LorentzSelfAttention — MI355X
//
// Degenerate-clamp simplification (verified analytically, passed R1-R23):
//   u_agg_i = C*(W_i + S_i*Q_i),  W_i = sum_j p_ij V_j,  p = exp(-d^2)*dist
//   S_i = -mink(Q_i, W_i)  [R9-verified identity]
//   Y_i = mink_normalize(Q_i + u_agg_i/sum_e), |time|
//   Ztan_i = dist0*C * (2*Y0, Ys)
//
// R24: barrier elimination. qkv + out_gemm converted to DIRECT fragment
// loads from global (L2-resident operands) with in-register bf16 convert:
// qkv loses all 16 k-loop barriers (epilogue barrier for FL kept), out_gemm
// loses LDS + all 10 barriers entirely. In the latency-bound regime (R18
// profile: <10% issue work) per-chunk barriers serialize every wave on the
// slowest load. attn R23-verbatim. out keeps hi/lo (no precision change).
// ---------------------------------------------------------------------------

namespace {

constexpr int Tq = 512;
constexpr int QS = 36;            // padded f32 Q row stride

#define EPSF  1e-6f
#define CINV  3.16227766e7f       // 1/sqrt(1e-15)

using short8 = __attribute__((ext_vector_type(8))) short;
using f32x4  = __attribute__((ext_vector_type(4))) float;

__device__ __forceinline__ float facosh(float x) {
    return __logf(x + __builtin_amdgcn_sqrtf(fmaf(x, x, -1.0f)));
}

__device__ __forceinline__ void cvt_hilo(float x, unsigned short& h, unsigned short& l) {
    const unsigned u = __float_as_uint(x);
    h = (unsigned short)(u >> 16);
    const float xh = __uint_as_float(u & 0xFFFF0000u);
    l = (unsigned short)(__float_as_uint(x - xh) >> 16);
}

__device__ __forceinline__ unsigned short cvt_rne(float x) {
    const unsigned u = __float_as_uint(x);
    return (unsigned short)((u + 0x7FFFu + ((u >> 16) & 1u)) >> 16);
}

__device__ __forceinline__ uint4 pack8(const unsigned short* s) {
    uint4 r;
    r.x = (unsigned)s[0] | ((unsigned)s[1] << 16);
    r.y = (unsigned)s[2] | ((unsigned)s[3] << 16);
    r.z = (unsigned)s[4] | ((unsigned)s[5] << 16);
    r.w = (unsigned)s[6] | ((unsigned)s[7] << 16);
    return r;
}

// load 8 consecutive f32, convert to bf16-RNE short8 fragment
__device__ __forceinline__ short8 frag_rne(const float* p) {
    const float4 a = *reinterpret_cast<const float4*>(p);
    const float4 b = *reinterpret_cast<const float4*>(p + 4);
    unsigned short s[8];
    s[0] = cvt_rne(a.x); s[1] = cvt_rne(a.y); s[2] = cvt_rne(a.z); s[3] = cvt_rne(a.w);
    s[4] = cvt_rne(b.x); s[5] = cvt_rne(b.y); s[6] = cvt_rne(b.z); s[7] = cvt_rne(b.w);
    const uint4 u = pack8(s);
    return *reinterpret_cast<const short8*>(&u);
}

// load 8 consecutive f32, split into hi/lo bf16 fragments
__device__ __forceinline__ void frag_hilo(const float* p, short8& hi, short8& lo) {
    const float4 a = *reinterpret_cast<const float4*>(p);
    const float4 b = *reinterpret_cast<const float4*>(p + 4);
    unsigned short h[8], l[8];
    cvt_hilo(a.x, h[0], l[0]); cvt_hilo(a.y, h[1], l[1]);
    cvt_hilo(a.z, h[2], l[2]); cvt_hilo(a.w, h[3], l[3]);
    cvt_hilo(b.x, h[4], l[4]); cvt_hilo(b.y, h[5], l[5]);
    cvt_hilo(b.z, h[6], l[6]); cvt_hilo(b.w, h[7], l[7]);
    const uint4 uh = pack8(h), ul = pack8(l);
    hi = *reinterpret_cast<const short8*>(&uh);
    lo = *reinterpret_cast<const short8*>(&ul);
}

// ---------------- Kernel 1: QKV GEMM, direct fragments, 0 k-barriers -------
__global__ __launch_bounds__(256) void gemm_qkv_mfma_kernel(
    const float* __restrict__ x,
    const float* __restrict__ Wq, const float* __restrict__ bq,
    const float* __restrict__ Wk, const float* __restrict__ bk,
    const float* __restrict__ Wv, const float* __restrict__ bv,
    float* __restrict__ Qf, unsigned short* __restrict__ Qh,
    unsigned short* __restrict__ Kh,
    unsigned short* __restrict__ Vh, unsigned short* __restrict__ V2h)
{
    __shared__ float sT[16][65];

    // XCD swizzle: 768 = 8 * 96
    const int bid = blockIdx.y * 12 + blockIdx.x;
    const int swz = (bid & 7) * 96 + (bid >> 3);
    const int n0 = (swz >> 6) * 64;
    const int m0 = (swz & 63) * 16;

    const int t  = threadIdx.x;
    const int l  = t & 63, w = t >> 6;
    const int wc = w * 16;
    const int fr = l & 15, fk = (l >> 4) * 8;

    const int which = n0 >> 8;                      // block-uniform
    const float* Wsel = (which == 0) ? Wq : (which == 1 ? Wk : Wv);
    const int obr = (n0 & 255) + wc + fr;           // W row for B fragment

    const float* xrow = x + (m0 + fr) * 512;
    const float* wrow = Wsel + obr * 512;

    f32x4 acc = (f32x4){0.f, 0.f, 0.f, 0.f};

    #pragma unroll 4
    for (int ks = 0; ks < 16; ++ks) {
        const int kb = ks * 32 + fk;
        const short8 ah = frag_rne(xrow + kb);
        const short8 bh = frag_rne(wrow + kb);
        acc = __builtin_amdgcn_mfma_f32_16x16x32_bf16(ah, bh, acc, 0, 0, 0);
    }

    #pragma unroll
    for (int r = 0; r < 4; ++r)
        sT[(l >> 4) * 4 + r][wc + fr] = acc[r];
    __syncthreads();

    // ---- FL lift + emission: 32 threads, one (row, head-half) each --------
    if (t < 32) {
        const int m = t >> 1, half = t & 1;
        const int row = m0 + m;
        const int b = row >> 9, tt = row & 511;
        const int h = ((n0 & 255) >> 5) + half;
        const int bh2 = b * 8 + h;
        const float* bsel = (which == 0) ? bq : (which == 1 ? bk : bv);

        float ys[32];
        float s2 = 0.f;
        #pragma unroll
        for (int k = 0; k < 32; ++k) {
            ys[k] = sT[m][half * 32 + k] + bsel[h * 32 + k];
            s2 = fmaf(ys[k], ys[k], s2);
        }
        const float rr = __builtin_amdgcn_sqrtf(s2);
        const float rs = fminf(fmaxf(rr, 1e-12f), 18.0f);
        const float e  = __expf(rs);
        const float ei = __builtin_amdgcn_rcpf(e);
        const float ch = 0.5f * (e + ei);
        float sc = 0.5f * (e - ei) / rs;
        if (rs < 1e-3f) sc = fmaf(rs * rs, 1.0f / 6.0f, 1.0f);
        float y0 = ch;
        float mink = -y0 * y0;
        #pragma unroll
        for (int k = 0; k < 32; ++k) { ys[k] *= sc; mink = fmaf(ys[k], ys[k], mink); }
        const float inv = __builtin_amdgcn_rsqf(fmaxf(fabsf(mink), 1e-15f));
        y0 = fabsf(y0 * inv);

        const long rbase = (long)(bh2 * Tq + tt) * 64;
        unsigned short hbuf[64];
        #pragma unroll
        for (int k = 33; k < 64; ++k) hbuf[k] = 0;

        if (which == 0) {
            float* qp = Qf + (bh2 * Tq + tt) * QS;
            #pragma unroll
            for (int c = 0; c < 8; ++c) {
                float4 v4;
                v4.x = ys[c*4+0] * inv; v4.y = ys[c*4+1] * inv;
                v4.z = ys[c*4+2] * inv; v4.w = ys[c*4+3] * inv;
                *reinterpret_cast<float4*>(qp + c * 4) = v4;
                hbuf[c*4+0] = cvt_rne(v4.x); hbuf[c*4+1] = cvt_rne(v4.y);
                hbuf[c*4+2] = cvt_rne(v4.z); hbuf[c*4+3] = cvt_rne(v4.w);
            }
            float4 tail; tail.x = y0; tail.y = 0.f; tail.z = 0.f; tail.w = 0.f;
            *reinterpret_cast<float4*>(qp + 32) = tail;
            hbuf[32] = cvt_rne(y0);
            #pragma unroll
            for (int c = 0; c < 8; ++c)
                *reinterpret_cast<uint4*>(&Qh[rbase + c * 8]) = pack8(hbuf + c * 8);
        } else if (which == 1) {
            #pragma unroll
            for (int k = 0; k < 32; ++k)
                hbuf[k] = cvt_rne(-ys[k] * inv);
            hbuf[32] = cvt_rne(y0);
            #pragma unroll
            for (int c = 0; c < 8; ++c)
                *reinterpret_cast<uint4*>(&Kh[rbase + c * 8]) = pack8(hbuf + c * 8);
        } else {
            const long v2b = (long)bh2 * 48 * Tq + tt;
            #pragma unroll
            for (int k = 0; k < 32; ++k) {
                const float v = ys[k] * inv;
                hbuf[k] = cvt_rne(-v);
                V2h[v2b + (1 + k) * Tq] = cvt_rne(v);
            }
            hbuf[32] = cvt_rne(y0);
            V2h[v2b] = cvt_rne(y0);
            #pragma unroll
            for (int c = 0; c < 8; ++c)
                *reinterpret_cast<uint4*>(&Vh[rbase + c * 8]) = pack8(hbuf + c * 8);
        }
    }
}

// ---------------- Kernel 2: attention, 512 threads, XCD-swizzled (R23) -----
__global__ __launch_bounds__(512) void attn_mfma_kernel(
    const float* __restrict__ Qf, const unsigned short* __restrict__ Qh,
    const unsigned short* __restrict__ Kh,
    const unsigned short* __restrict__ Vh, const unsigned short* __restrict__ V2h,
    float* __restrict__ Ztan)
{
    __shared__ unsigned short sPh[16][528];
    __shared__ float sSe[8][16];
    __shared__ float sWp[2][16][48];

    // XCD swizzle: 512 = 8 * 64
    const int bid = blockIdx.y * 32 + blockIdx.x;
    const int swz = (bid & 7) * 64 + (bid >> 3);
    const int bh = swz >> 5;
    const int i0 = (swz & 31) * 16;

    const int t  = threadIdx.x;
    const int l  = t & 63, w = t >> 6;
    const int fr = l & 15, fk = (l >> 4) * 8;

    short8 qh[2];
    {
        const long qb = (long)(bh * Tq + i0 + fr) * 64;
        #pragma unroll
        for (int ks = 0; ks < 2; ++ks)
            qh[ks] = *reinterpret_cast<const short8*>(&Qh[qb + ks * 32 + fk]);
    }

    float seLoc[4] = {0.f, 0.f, 0.f, 0.f};
    #pragma unroll
    for (int c = 0; c < 4; ++c) {
        const int j0 = (w * 4 + c) * 16;
        const long kb = (long)(bh * Tq + j0 + fr) * 64;
        f32x4 aK = (f32x4){0.f, 0.f, 0.f, 0.f};
        f32x4 aV = (f32x4){0.f, 0.f, 0.f, 0.f};
        #pragma unroll
        for (int ks = 0; ks < 2; ++ks) {
            const long o = kb + ks * 32 + fk;
            const short8 bkh = *reinterpret_cast<const short8*>(&Kh[o]);
            const short8 bvh = *reinterpret_cast<const short8*>(&Vh[o]);
            aK = __builtin_amdgcn_mfma_f32_16x16x32_bf16(qh[ks], bkh, aK, 0, 0, 0);
            aV = __builtin_amdgcn_mfma_f32_16x16x32_bf16(qh[ks], bvh, aV, 0, 0, 0);
        }
        #pragma unroll
        for (int r = 0; r < 4; ++r) {
            const int i = (l >> 4) * 4 + r;
            const int j = j0 + fr;
            const float d  = facosh(fmaxf(aK[r], 1.0f + EPSF));
            const float al = fmaxf(aV[r], 1.0f + EPSF);
            const float e  = __expf(-d * d);
            const float p  = e * facosh(al);
            seLoc[r] += e;
            sPh[i][j] = cvt_rne(p);
        }
    }
    #pragma unroll
    for (int r = 0; r < 4; ++r) {
        float v = seLoc[r];
        v += __shfl_xor(v, 1, 64);
        v += __shfl_xor(v, 2, 64);
        v += __shfl_xor(v, 4, 64);
        v += __shfl_xor(v, 8, 64);
        if ((l & 15) == 0) sSe[w][(l >> 4) * 4 + r] = v;
    }
    __syncthreads();

    if (w < 6) {
        const int a0  = (w % 3) * 16;
        const int kh2 = w / 3;
        const long vb = (long)bh * 48 * Tq + (long)(a0 + fr) * Tq;
        f32x4 aW = (f32x4){0.f, 0.f, 0.f, 0.f};
        #pragma unroll 4
        for (int ks = kh2 * 8; ks < kh2 * 8 + 8; ++ks) {
            const int ko = ks * 32 + fk;
            const short8 ph  = *reinterpret_cast<const short8*>(&sPh[fr][ko]);
            const short8 v2h = *reinterpret_cast<const short8*>(&V2h[vb + ko]);
            aW = __builtin_amdgcn_mfma_f32_16x16x32_bf16(ph, v2h, aW, 0, 0, 0);
        }
        #pragma unroll
        for (int r = 0; r < 4; ++r)
            sWp[kh2][(l >> 4) * 4 + r][a0 + fr] = aW[r];
    }
    __syncthreads();

    if (t < 16) {
        const int i = t;
        float seT = 0.f;
        #pragma unroll
        for (int ww = 0; ww < 8; ++ww) seT += sSe[ww][i];
        float W[33];
        #pragma unroll
        for (int a = 0; a < 33; ++a) W[a] = sWp[0][i][a] + sWp[1][i][a];
        const float* qrow = Qf + (long)(bh * Tq + i0 + i) * QS;
        const float q0 = qrow[32];
        float dot = 0.f;
        #pragma unroll
        for (int a = 1; a < 33; ++a) dot = fmaf(qrow[a - 1], W[a], dot);
        const float S = q0 * W[0] - dot;
        const float cs = CINV * __builtin_amdgcn_rcpf(seT);
        const float y0 = fmaf(cs, fmaf(S, q0, W[0]), q0);
        float mink = -y0 * y0;
        float yv[32];
        #pragma unroll
        for (int a = 1; a < 33; ++a) {
            const float qa = qrow[a - 1];
            const float ya = fmaf(cs, fmaf(S, qa, W[a]), qa);
            yv[a - 1] = ya;
            mink = fmaf(ya, ya, mink);
        }
        const float inv = __builtin_amdgcn_rsqf(fmaxf(fabsf(mink), 1e-15f));
        const float Y0 = fabsf(y0 * inv);
        const float dist0 = facosh(fmaxf(Y0, 1.0f + EPSF));
        const float coef = dist0 * CINV;
        const int b = bh >> 3, h = bh & 7;
        float* zp = Ztan + ((b * Tq + (i0 + i)) * 264) + h * 33;
        zp[0] = coef * (2.0f * Y0);
        #pragma unroll
        for (int a = 1; a < 33; ++a) zp[a] = coef * (yv[a - 1] * inv);
    }
}

// ---------------- Kernel 3: out GEMM, direct fragments, 0 barriers ---------
// out[1024][512] = Ztan[1024][264] @ Wo^T + bo. 264 = 8*32 + 8 (8-aligned
// fragment tail: only fk=0 lanes have valid data at k0=256).
__global__ __launch_bounds__(256) void out_gemm_mfma_kernel(
    const float* __restrict__ Ztan, const float* __restrict__ Wo,
    const float* __restrict__ bo, float* __restrict__ out)
{
    const int n0 = blockIdx.x * 32;
    const int m0 = blockIdx.y * 32;
    const int t  = threadIdx.x;
    const int l  = t & 63, w = t >> 6;
    const int wr = (w >> 1) * 16, wc = (w & 1) * 16;
    const int fr = l & 15, fk = (l >> 4) * 8;

    const float* arow = Ztan + (m0 + wr + fr) * 264;
    const float* brow = Wo + (n0 + wc + fr) * 264;

    f32x4 acc = (f32x4){0.f, 0.f, 0.f, 0.f};

    #pragma unroll
    for (int ks = 0; ks < 9; ++ks) {
        const int kb = ks * 32 + fk;
        short8 ah, al_, bh, bl_;
        if (kb + 8 <= 264) {
            frag_hilo(arow + kb, ah, al_);
            frag_hilo(brow + kb, bh, bl_);
        } else {
            const short8 z = (short8){0, 0, 0, 0, 0, 0, 0, 0};
            ah = z; al_ = z; bh = z; bl_ = z;
        }
        acc = __builtin_amdgcn_mfma_f32_16x16x32_bf16(ah, bh, acc, 0, 0, 0);
        acc = __builtin_amdgcn_mfma_f32_16x16x32_bf16(ah, bl_, acc, 0, 0, 0);
        acc = __builtin_amdgcn_mfma_f32_16x16x32_bf16(al_, bh, acc, 0, 0, 0);
    }

    const int col = n0 + wc + fr;
    const float bias = bo[col];
    #pragma unroll
    for (int r = 0; r < 4; ++r) {
        const int row = m0 + wr + (l >> 4) * 4 + r;
        out[row * 512 + col] = acc[r] + bias;
    }
}

} // namespace

// ---------------------------------------------------------------------------
extern "C" void kernel_launch(void* const* d_in, const int* in_sizes, int n_in,
                              void* d_out, int out_size, void* d_ws, size_t ws_size,
                              hipStream_t stream)
{
    const float* x  = (const float*)d_in[0];
    const float* Wq = (const float*)d_in[1];
    const float* bq = (const float*)d_in[2];
    const float* Wk = (const float*)d_in[3];
    const float* bk = (const float*)d_in[4];
    const float* Wv = (const float*)d_in[5];
    const float* bv = (const float*)d_in[6];
    const float* Wo = (const float*)d_in[7];
    const float* bo = (const float*)d_in[8];
    float* out = (float*)d_out;

    float* ws = (float*)d_ws;
    float* Qf = ws;                                   // 294912 f
    unsigned short* Qh  = (unsigned short*)(ws + 294912);   // 262144 f each
    unsigned short* Kh  = (unsigned short*)(ws + 557056);
    unsigned short* Vh  = (unsigned short*)(ws + 819200);
    unsigned short* V2h = (unsigned short*)(ws + 1081344);  // 196608 f
    float* Zt = ws + 1277952;                         // 270336 f

    gemm_qkv_mfma_kernel<<<dim3(12, 64), 256, 0, stream>>>(
        x, Wq, bq, Wk, bk, Wv, bv, Qf, Qh, Kh, Vh, V2h);
    attn_mfma_kernel<<<dim3(32, 16), 512, 0, stream>>>(
        Qf, Qh, Kh, Vh, V2h, Zt);
    out_gemm_mfma_kernel<<<dim3(16, 32), 256, 0, stream>>>(Zt, Wo, bo, out);
}

// Round 25
// 37.268 us; speedup vs baseline: 1.4036x; 1.4036x over previous
//
#include <hip/hip_runtime.h>
#include <math.h>

// ---------------------------------------------------------------------------
// LorentzSelfAttention — MI355X
//
// Degenerate-clamp simplification (verified analytically, passed R1-R24):
//   u_agg_i = C*(W_i + S_i*Q_i),  W_i = sum_j p_ij V_j,  p = exp(-d^2)*dist
//   S_i = -mink(Q_i, W_i)  [R9-verified identity]
//   Y_i = mink_normalize(Q_i + u_agg_i/sum_e), |time|
//   Ztan_i = dist0*C * (2*Y0, Ys)
//
// R25 = exact revert to R23 (best measured: 37.3us). R24's direct-fragment
// experiment REGRESSED +15us: LDS staging provides coalescing (contiguous
// 1KB wave reads vs 64x32B scattered) + A-tile reuse (1x LDS vs 4x L2),
// not just sync — barriers were NOT the cost. Lesson: direct fragment loads
// only pay when the buffer layout IS the fragment layout (attn's Kh/Vh).
// ---------------------------------------------------------------------------

namespace {

constexpr int Tq = 512;
constexpr int QS = 36;            // padded f32 Q row stride

#define EPSF  1e-6f
#define CINV  3.16227766e7f       // 1/sqrt(1e-15)

using short8 = __attribute__((ext_vector_type(8))) short;
using f32x4  = __attribute__((ext_vector_type(4))) float;

__device__ __forceinline__ float facosh(float x) {
    return __logf(x + __builtin_amdgcn_sqrtf(fmaf(x, x, -1.0f)));
}

__device__ __forceinline__ void cvt_hilo(float x, unsigned short& h, unsigned short& l) {
    const unsigned u = __float_as_uint(x);
    h = (unsigned short)(u >> 16);
    const float xh = __uint_as_float(u & 0xFFFF0000u);
    l = (unsigned short)(__float_as_uint(x - xh) >> 16);
}

__device__ __forceinline__ unsigned short cvt_rne(float x) {
    const unsigned u = __float_as_uint(x);
    return (unsigned short)((u + 0x7FFFu + ((u >> 16) & 1u)) >> 16);
}

__device__ __forceinline__ uint4 pack8(const unsigned short* s) {
    uint4 r;
    r.x = (unsigned)s[0] | ((unsigned)s[1] << 16);
    r.y = (unsigned)s[2] | ((unsigned)s[3] << 16);
    r.z = (unsigned)s[4] | ((unsigned)s[5] << 16);
    r.w = (unsigned)s[6] | ((unsigned)s[7] << 16);
    return r;
}

// ---------------- Kernel 1: QKV GEMM, single-RNE bf16, 16x64 tiles ---------
__global__ __launch_bounds__(256) void gemm_qkv_mfma_kernel(
    const float* __restrict__ x,
    const float* __restrict__ Wq, const float* __restrict__ bq,
    const float* __restrict__ Wk, const float* __restrict__ bk,
    const float* __restrict__ Wv, const float* __restrict__ bv,
    float* __restrict__ Qf, unsigned short* __restrict__ Qh,
    unsigned short* __restrict__ Kh,
    unsigned short* __restrict__ Vh, unsigned short* __restrict__ V2h)
{
    __shared__ unsigned short Ah[16][72];
    __shared__ unsigned short Bh[64][72];
    __shared__ float sT[16][65];

    // XCD swizzle: 768 = 8 * 96
    const int bid = blockIdx.y * 12 + blockIdx.x;
    const int swz = (bid & 7) * 96 + (bid >> 3);
    const int n0 = (swz >> 6) * 64;
    const int m0 = (swz & 63) * 16;

    const int t  = threadIdx.x;
    const int l  = t & 63, w = t >> 6;
    const int wc = w * 16;
    const int fr = l & 15, fk = (l >> 4) * 8;

    const int arow = t >> 4, akseg = (t & 15) * 4;
    const int brow = t >> 2, bkseg = (t & 3) * 16;
    const int ob  = n0 + brow;
    const float* WselB = (ob < 256) ? Wq : (ob < 512 ? Wk : Wv);
    const int obr = ob & 255;

    f32x4 acc = (f32x4){0.f, 0.f, 0.f, 0.f};

    for (int k0 = 0; k0 < 512; k0 += 64) {
        {
            const float4 av = *reinterpret_cast<const float4*>(
                &x[(m0 + arow) * 512 + k0 + akseg]);
            uint2 H;
            H.x = (unsigned)cvt_rne(av.x) | ((unsigned)cvt_rne(av.y) << 16);
            H.y = (unsigned)cvt_rne(av.z) | ((unsigned)cvt_rne(av.w) << 16);
            *reinterpret_cast<uint2*>(&Ah[arow][akseg]) = H;

            const float* wp = WselB + obr * 512 + k0 + bkseg;
            unsigned short hh[16];
            #pragma unroll
            for (int c = 0; c < 4; ++c) {
                const float4 v = *reinterpret_cast<const float4*>(wp + c * 4);
                hh[c*4+0] = cvt_rne(v.x); hh[c*4+1] = cvt_rne(v.y);
                hh[c*4+2] = cvt_rne(v.z); hh[c*4+3] = cvt_rne(v.w);
            }
            *reinterpret_cast<uint4*>(&Bh[brow][bkseg])     = pack8(hh);
            *reinterpret_cast<uint4*>(&Bh[brow][bkseg + 8]) = pack8(hh + 8);
        }
        __syncthreads();

        #pragma unroll
        for (int ks = 0; ks < 2; ++ks) {
            const int kb = ks * 32 + fk;
            const short8 ah = *reinterpret_cast<const short8*>(&Ah[fr][kb]);
            const short8 bh = *reinterpret_cast<const short8*>(&Bh[wc + fr][kb]);
            acc = __builtin_amdgcn_mfma_f32_16x16x32_bf16(ah, bh, acc, 0, 0, 0);
        }
        __syncthreads();
    }

    #pragma unroll
    for (int r = 0; r < 4; ++r)
        sT[(l >> 4) * 4 + r][wc + fr] = acc[r];
    __syncthreads();

    if (t < 32) {
        const int m = t >> 1, half = t & 1;
        const int row = m0 + m;
        const int b = row >> 9, tt = row & 511;
        const int which = n0 >> 8;
        const int h = ((n0 & 255) >> 5) + half;
        const int bh2 = b * 8 + h;
        const float* bsel = (which == 0) ? bq : (which == 1 ? bk : bv);

        float ys[32];
        float s2 = 0.f;
        #pragma unroll
        for (int k = 0; k < 32; ++k) {
            ys[k] = sT[m][half * 32 + k] + bsel[h * 32 + k];
            s2 = fmaf(ys[k], ys[k], s2);
        }
        const float rr = __builtin_amdgcn_sqrtf(s2);
        const float rs = fminf(fmaxf(rr, 1e-12f), 18.0f);
        const float e  = __expf(rs);
        const float ei = __builtin_amdgcn_rcpf(e);
        const float ch = 0.5f * (e + ei);
        float sc = 0.5f * (e - ei) / rs;
        if (rs < 1e-3f) sc = fmaf(rs * rs, 1.0f / 6.0f, 1.0f);
        float y0 = ch;
        float mink = -y0 * y0;
        #pragma unroll
        for (int k = 0; k < 32; ++k) { ys[k] *= sc; mink = fmaf(ys[k], ys[k], mink); }
        const float inv = __builtin_amdgcn_rsqf(fmaxf(fabsf(mink), 1e-15f));
        y0 = fabsf(y0 * inv);

        const long rbase = (long)(bh2 * Tq + tt) * 64;
        unsigned short hbuf[64];
        #pragma unroll
        for (int k = 33; k < 64; ++k) hbuf[k] = 0;

        if (which == 0) {
            float* qp = Qf + (bh2 * Tq + tt) * QS;
            #pragma unroll
            for (int c = 0; c < 8; ++c) {
                float4 v4;
                v4.x = ys[c*4+0] * inv; v4.y = ys[c*4+1] * inv;
                v4.z = ys[c*4+2] * inv; v4.w = ys[c*4+3] * inv;
                *reinterpret_cast<float4*>(qp + c * 4) = v4;
                hbuf[c*4+0] = cvt_rne(v4.x); hbuf[c*4+1] = cvt_rne(v4.y);
                hbuf[c*4+2] = cvt_rne(v4.z); hbuf[c*4+3] = cvt_rne(v4.w);
            }
            float4 tail; tail.x = y0; tail.y = 0.f; tail.z = 0.f; tail.w = 0.f;
            *reinterpret_cast<float4*>(qp + 32) = tail;
            hbuf[32] = cvt_rne(y0);
            #pragma unroll
            for (int c = 0; c < 8; ++c)
                *reinterpret_cast<uint4*>(&Qh[rbase + c * 8]) = pack8(hbuf + c * 8);
        } else if (which == 1) {
            #pragma unroll
            for (int k = 0; k < 32; ++k)
                hbuf[k] = cvt_rne(-ys[k] * inv);
            hbuf[32] = cvt_rne(y0);
            #pragma unroll
            for (int c = 0; c < 8; ++c)
                *reinterpret_cast<uint4*>(&Kh[rbase + c * 8]) = pack8(hbuf + c * 8);
        } else {
            const long v2b = (long)bh2 * 48 * Tq + tt;
            #pragma unroll
            for (int k = 0; k < 32; ++k) {
                const float v = ys[k] * inv;
                hbuf[k] = cvt_rne(-v);
                V2h[v2b + (1 + k) * Tq] = cvt_rne(v);
            }
            hbuf[32] = cvt_rne(y0);
            V2h[v2b] = cvt_rne(y0);
            #pragma unroll
            for (int c = 0; c < 8; ++c)
                *reinterpret_cast<uint4*>(&Vh[rbase + c * 8]) = pack8(hbuf + c * 8);
        }
    }
}

// ---------------- Kernel 2: attention, 512 threads, XCD-swizzled -----------
__global__ __launch_bounds__(512) void attn_mfma_kernel(
    const float* __restrict__ Qf, const unsigned short* __restrict__ Qh,
    const unsigned short* __restrict__ Kh,
    const unsigned short* __restrict__ Vh, const unsigned short* __restrict__ V2h,
    float* __restrict__ Ztan)
{
    __shared__ unsigned short sPh[16][528];
    __shared__ float sSe[8][16];
    __shared__ float sWp[2][16][48];

    // XCD swizzle: 512 = 8 * 64
    const int bid = blockIdx.y * 32 + blockIdx.x;
    const int swz = (bid & 7) * 64 + (bid >> 3);
    const int bh = swz >> 5;
    const int i0 = (swz & 31) * 16;

    const int t  = threadIdx.x;
    const int l  = t & 63, w = t >> 6;
    const int fr = l & 15, fk = (l >> 4) * 8;

    short8 qh[2];
    {
        const long qb = (long)(bh * Tq + i0 + fr) * 64;
        #pragma unroll
        for (int ks = 0; ks < 2; ++ks)
            qh[ks] = *reinterpret_cast<const short8*>(&Qh[qb + ks * 32 + fk]);
    }

    float seLoc[4] = {0.f, 0.f, 0.f, 0.f};
    #pragma unroll
    for (int c = 0; c < 4; ++c) {
        const int j0 = (w * 4 + c) * 16;
        const long kb = (long)(bh * Tq + j0 + fr) * 64;
        f32x4 aK = (f32x4){0.f, 0.f, 0.f, 0.f};
        f32x4 aV = (f32x4){0.f, 0.f, 0.f, 0.f};
        #pragma unroll
        for (int ks = 0; ks < 2; ++ks) {
            const long o = kb + ks * 32 + fk;
            const short8 bkh = *reinterpret_cast<const short8*>(&Kh[o]);
            const short8 bvh = *reinterpret_cast<const short8*>(&Vh[o]);
            aK = __builtin_amdgcn_mfma_f32_16x16x32_bf16(qh[ks], bkh, aK, 0, 0, 0);
            aV = __builtin_amdgcn_mfma_f32_16x16x32_bf16(qh[ks], bvh, aV, 0, 0, 0);
        }
        #pragma unroll
        for (int r = 0; r < 4; ++r) {
            const int i = (l >> 4) * 4 + r;
            const int j = j0 + fr;
            const float d  = facosh(fmaxf(aK[r], 1.0f + EPSF));
            const float al = fmaxf(aV[r], 1.0f + EPSF);
            const float e  = __expf(-d * d);
            const float p  = e * facosh(al);
            seLoc[r] += e;
            sPh[i][j] = cvt_rne(p);
        }
    }
    #pragma unroll
    for (int r = 0; r < 4; ++r) {
        float v = seLoc[r];
        v += __shfl_xor(v, 1, 64);
        v += __shfl_xor(v, 2, 64);
        v += __shfl_xor(v, 4, 64);
        v += __shfl_xor(v, 8, 64);
        if ((l & 15) == 0) sSe[w][(l >> 4) * 4 + r] = v;
    }
    __syncthreads();

    if (w < 6) {
        const int a0  = (w % 3) * 16;
        const int kh2 = w / 3;
        const long vb = (long)bh * 48 * Tq + (long)(a0 + fr) * Tq;
        f32x4 aW = (f32x4){0.f, 0.f, 0.f, 0.f};
        #pragma unroll 4
        for (int ks = kh2 * 8; ks < kh2 * 8 + 8; ++ks) {
            const int ko = ks * 32 + fk;
            const short8 ph  = *reinterpret_cast<const short8*>(&sPh[fr][ko]);
            const short8 v2h = *reinterpret_cast<const short8*>(&V2h[vb + ko]);
            aW = __builtin_amdgcn_mfma_f32_16x16x32_bf16(ph, v2h, aW, 0, 0, 0);
        }
        #pragma unroll
        for (int r = 0; r < 4; ++r)
            sWp[kh2][(l >> 4) * 4 + r][a0 + fr] = aW[r];
    }
    __syncthreads();

    if (t < 16) {
        const int i = t;
        float seT = 0.f;
        #pragma unroll
        for (int ww = 0; ww < 8; ++ww) seT += sSe[ww][i];
        float W[33];
        #pragma unroll
        for (int a = 0; a < 33; ++a) W[a] = sWp[0][i][a] + sWp[1][i][a];
        const float* qrow = Qf + (long)(bh * Tq + i0 + i) * QS;
        const float q0 = qrow[32];
        float dot = 0.f;
        #pragma unroll
        for (int a = 1; a < 33; ++a) dot = fmaf(qrow[a - 1], W[a], dot);
        const float S = q0 * W[0] - dot;
        const float cs = CINV * __builtin_amdgcn_rcpf(seT);
        const float y0 = fmaf(cs, fmaf(S, q0, W[0]), q0);
        float mink = -y0 * y0;
        float yv[32];
        #pragma unroll
        for (int a = 1; a < 33; ++a) {
            const float qa = qrow[a - 1];
            const float ya = fmaf(cs, fmaf(S, qa, W[a]), qa);
            yv[a - 1] = ya;
            mink = fmaf(ya, ya, mink);
        }
        const float inv = __builtin_amdgcn_rsqf(fmaxf(fabsf(mink), 1e-15f));
        const float Y0 = fabsf(y0 * inv);
        const float dist0 = facosh(fmaxf(Y0, 1.0f + EPSF));
        const float coef = dist0 * CINV;
        const int b = bh >> 3, h = bh & 7;
        float* zp = Ztan + ((b * Tq + (i0 + i)) * 264) + h * 33;
        zp[0] = coef * (2.0f * Y0);
        #pragma unroll
        for (int a = 1; a < 33; ++a) zp[a] = coef * (yv[a - 1] * inv);
    }
}

// ---------------- Kernel 3: out GEMM via MFMA hi/lo ------------------------
__global__ __launch_bounds__(256) void out_gemm_mfma_kernel(
    const float* __restrict__ Ztan, const float* __restrict__ Wo,
    const float* __restrict__ bo, float* __restrict__ out)
{
    __shared__ unsigned short Ah[32][72], Al[32][72];
    __shared__ unsigned short Bh[32][72], Bl[32][72];

    const int n0 = blockIdx.x * 32;
    const int m0 = blockIdx.y * 32;
    const int t  = threadIdx.x;
    const int l  = t & 63, w = t >> 6;
    const int wr = (w >> 1) * 16, wc = (w & 1) * 16;
    const int fr = l & 15, fk = (l >> 4) * 8;

    const int sr = t >> 3, sk = (t & 7) * 8;

    f32x4 acc = (f32x4){0.f, 0.f, 0.f, 0.f};

    for (int k0 = 0; k0 < 264; k0 += 64) {
        const bool full = (k0 + sk + 7 < 264);
        {
            unsigned short h8[8], l8[8];
            if (full) {
                const float4 a0v = *reinterpret_cast<const float4*>(
                    &Ztan[(m0 + sr) * 264 + k0 + sk]);
                const float4 a1v = *reinterpret_cast<const float4*>(
                    &Ztan[(m0 + sr) * 264 + k0 + sk + 4]);
                cvt_hilo(a0v.x, h8[0], l8[0]); cvt_hilo(a0v.y, h8[1], l8[1]);
                cvt_hilo(a0v.z, h8[2], l8[2]); cvt_hilo(a0v.w, h8[3], l8[3]);
                cvt_hilo(a1v.x, h8[4], l8[4]); cvt_hilo(a1v.y, h8[5], l8[5]);
                cvt_hilo(a1v.z, h8[6], l8[6]); cvt_hilo(a1v.w, h8[7], l8[7]);
            } else {
                #pragma unroll
                for (int c = 0; c < 8; ++c) { h8[c] = 0; l8[c] = 0; }
            }
            *reinterpret_cast<uint4*>(&Ah[sr][sk]) = pack8(h8);
            *reinterpret_cast<uint4*>(&Al[sr][sk]) = pack8(l8);

            if (full) {
                const float4 b0v = *reinterpret_cast<const float4*>(
                    &Wo[(n0 + sr) * 264 + k0 + sk]);
                const float4 b1v = *reinterpret_cast<const float4*>(
                    &Wo[(n0 + sr) * 264 + k0 + sk + 4]);
                cvt_hilo(b0v.x, h8[0], l8[0]); cvt_hilo(b0v.y, h8[1], l8[1]);
                cvt_hilo(b0v.z, h8[2], l8[2]); cvt_hilo(b0v.w, h8[3], l8[3]);
                cvt_hilo(b1v.x, h8[4], l8[4]); cvt_hilo(b1v.y, h8[5], l8[5]);
                cvt_hilo(b1v.z, h8[6], l8[6]); cvt_hilo(b1v.w, h8[7], l8[7]);
            } else {
                #pragma unroll
                for (int c = 0; c < 8; ++c) { h8[c] = 0; l8[c] = 0; }
            }
            *reinterpret_cast<uint4*>(&Bh[sr][sk]) = pack8(h8);
            *reinterpret_cast<uint4*>(&Bl[sr][sk]) = pack8(l8);
        }
        __syncthreads();

        #pragma unroll
        for (int ks = 0; ks < 2; ++ks) {
            const int kb = ks * 32 + fk;
            const short8 ah  = *reinterpret_cast<const short8*>(&Ah[wr + fr][kb]);
            const short8 al_ = *reinterpret_cast<const short8*>(&Al[wr + fr][kb]);
            const short8 bh  = *reinterpret_cast<const short8*>(&Bh[wc + fr][kb]);
            const short8 bl_ = *reinterpret_cast<const short8*>(&Bl[wc + fr][kb]);
            acc = __builtin_amdgcn_mfma_f32_16x16x32_bf16(ah, bh, acc, 0, 0, 0);
            acc = __builtin_amdgcn_mfma_f32_16x16x32_bf16(ah, bl_, acc, 0, 0, 0);
            acc = __builtin_amdgcn_mfma_f32_16x16x32_bf16(al_, bh, acc, 0, 0, 0);
        }
        __syncthreads();
    }

    const int col = n0 + wc + fr;
    const float bias = bo[col];
    #pragma unroll
    for (int r = 0; r < 4; ++r) {
        const int row = m0 + wr + (l >> 4) * 4 + r;
        out[row * 512 + col] = acc[r] + bias;
    }
}

} // namespace

// ---------------------------------------------------------------------------
extern "C" void kernel_launch(void* const* d_in, const int* in_sizes, int n_in,
                              void* d_out, int out_size, void* d_ws, size_t ws_size,
                              hipStream_t stream)
{
    const float* x  = (const float*)d_in[0];
    const float* Wq = (const float*)d_in[1];
    const float* bq = (const float*)d_in[2];
    const float* Wk = (const float*)d_in[3];
    const float* bk = (const float*)d_in[4];
    const float* Wv = (const float*)d_in[5];
    const float* bv = (const float*)d_in[6];
    const float* Wo = (const float*)d_in[7];
    const float* bo = (const float*)d_in[8];
    float* out = (float*)d_out;

    float* ws = (float*)d_ws;
    float* Qf = ws;                                   // 294912 f
    unsigned short* Qh  = (unsigned short*)(ws + 294912);   // 262144 f each
    unsigned short* Kh  = (unsigned short*)(ws + 557056);
    unsigned short* Vh  = (unsigned short*)(ws + 819200);
    unsigned short* V2h = (unsigned short*)(ws + 1081344);  // 196608 f
    float* Zt = ws + 1277952;                         // 270336 f

    gemm_qkv_mfma_kernel<<<dim3(12, 64), 256, 0, stream>>>(
        x, Wq, bq, Wk, bk, Wv, bv, Qf, Qh, Kh, Vh, V2h);
    attn_mfma_kernel<<<dim3(32, 16), 512, 0, stream>>>(
        Qf, Qh, Kh, Vh, V2h, Zt);
    out_gemm_mfma_kernel<<<dim3(16, 32), 256, 0, stream>>>(Zt, Wo, bo, out);
}